// Round 2
// baseline (3934.681 us; speedup 1.0000x reference)
//
#include <hip/hip_runtime.h>

#define NEG_SLOPE 0.1f

static inline int cdiv(int a, int b) { return (a + b - 1) / b; }

// Compile-time geometry: interior rectangle (no bounds checks needed) vs edge ring.
template <int K, int S, int PAD, int HIN, int WIN, int HOUT, int WOUT, int TW>
struct Geom {
    static constexpr int SLOTS_W = WOUT / TW;       // thread-slots per output row
    static constexpr int NSLOT   = HOUT * SLOTS_W;  // slots per (b, co_group) plane
    static constexpr int L       = (TW - 1) * S + K;
    // interior rows: ho*S-PAD >= 0  and  ho*S-PAD+K <= HIN
    static constexpr int HO_LO   = (PAD + S - 1) / S;
    static constexpr int HO_HI0  = (HIN - K + PAD) / S + 1;
    static constexpr int HO_HI   = HO_HI0 < HOUT ? HO_HI0 : HOUT;
    // interior col-slots: ws*TW*S-PAD >= 0  and  ws*TW*S-PAD+L <= WIN
    static constexpr int WS_LO   = (PAD + TW * S - 1) / (TW * S);
    static constexpr int WS_HI0  = (WIN + PAD - L) / (TW * S) + 1;
    static constexpr int WS_HI   = WS_HI0 < SLOTS_W ? WS_HI0 : SLOTS_W;
    static constexpr int WS_N    = WS_HI - WS_LO;
    static constexpr int N_INT   = (HO_HI - HO_LO) * WS_N;
    static constexpr int N_EDGE  = NSLOT - N_INT;
};

// ---------------- interior conv + leaky relu (no bounds checks at all) ----------------
template <int K, int S, int PAD, int CIN, int COUT,
          int HIN, int WIN, int HOUT, int WOUT, int TCO, int TW>
__global__ __launch_bounds__(256, 4) void conv_int(const float* __restrict__ x,
                                                   const float* __restrict__ w,
                                                   const float* __restrict__ bs,
                                                   float* __restrict__ y) {
    using G = Geom<K, S, PAD, HIN, WIN, HOUT, WOUT, TW>;
    constexpr int NW = TCO * CIN * K * K;

    __shared__ float wlds[NW];

    const int zz  = blockIdx.z;
    const int b   = zz / (COUT / TCO);
    const int cob = (zz % (COUT / TCO)) * TCO;

    // stage weights: wlds[((ci*K+kh)*K+kw)*TCO + t] = w[(cob+t)][ci][kh][kw]
    for (int i = threadIdx.x; i < NW; i += 256) {
        int t    = i % TCO;
        int rest = i / TCO;
        wlds[i] = w[(size_t)(cob + t) * (CIN * K * K) + rest];
    }
    __syncthreads();

    const int s = blockIdx.x * 256 + threadIdx.x;
    if (s >= G::N_INT) return;

    const int ho = G::HO_LO + s / G::WS_N;
    const int wo = (G::WS_LO + s % G::WS_N) * TW;

    const float* xb = x + (size_t)b * CIN * HIN * WIN;

    float acc[TCO][TW];
#pragma unroll
    for (int t = 0; t < TCO; ++t) {
        float bv = bs[cob + t];
#pragma unroll
        for (int j = 0; j < TW; ++j) acc[t][j] = bv;
    }

    const int hi0 = ho * S - PAD;
    const int wi0 = wo * S - PAD;

    auto cibody = [&](int ci) {
        const float* xc = xb + (size_t)ci * HIN * WIN;
        const float* wc = &wlds[(ci * K * K) * TCO];
#pragma unroll
        for (int kh = 0; kh < K; ++kh) {
            const float* xr = xc + (size_t)(hi0 + kh) * WIN + wi0;
            float r[G::L];
#pragma unroll
            for (int u = 0; u < G::L; ++u) r[u] = xr[u];
#pragma unroll
            for (int kw = 0; kw < K; ++kw) {
                const float* wg = wc + (kh * K + kw) * TCO;
                float w8[TCO];
                if constexpr ((TCO % 4) == 0) {
#pragma unroll
                    for (int t = 0; t < TCO; t += 4) {
                        float4 q = *reinterpret_cast<const float4*>(wg + t);
                        w8[t] = q.x; w8[t + 1] = q.y; w8[t + 2] = q.z; w8[t + 3] = q.w;
                    }
                } else {
#pragma unroll
                    for (int t = 0; t < TCO; ++t) w8[t] = wg[t];
                }
#pragma unroll
                for (int j = 0; j < TW; ++j) {
                    const float xv = r[kw + j * S];
#pragma unroll
                    for (int t = 0; t < TCO; ++t)
                        acc[t][j] = fmaf(xv, w8[t], acc[t][j]);
                }
            }
        }
    };

    if constexpr (CIN <= 8) {
#pragma unroll
        for (int ci = 0; ci < CIN; ++ci) cibody(ci);
    } else {
#pragma unroll 4
        for (int ci = 0; ci < CIN; ++ci) cibody(ci);
    }

    // epilogue: leaky relu + vectorized store (wo, WOUT multiples of TW -> 8/16B aligned)
#pragma unroll
    for (int t = 0; t < TCO; ++t) {
        float* yr = y + (((size_t)b * COUT + cob + t) * HOUT + ho) * WOUT + wo;
        float v[TW];
#pragma unroll
        for (int j = 0; j < TW; ++j) {
            const float a = acc[t][j];
            v[j] = a >= 0.0f ? a : NEG_SLOPE * a;
        }
        if constexpr (TW == 4) {
            *reinterpret_cast<float4*>(yr) = make_float4(v[0], v[1], v[2], v[3]);
        } else if constexpr (TW == 2) {
            *reinterpret_cast<float2*>(yr) = make_float2(v[0], v[1]);
        } else {
#pragma unroll
            for (int j = 0; j < TW; ++j) yr[j] = v[j];
        }
    }
}

// ---------------- edge conv + leaky relu (clamped loads, tiny work) ----------------
template <int K, int S, int PAD, int CIN, int COUT,
          int HIN, int WIN, int HOUT, int WOUT, int TCO, int TW>
__global__ __launch_bounds__(256) void conv_edge(const float* __restrict__ x,
                                                 const float* __restrict__ w,
                                                 const float* __restrict__ bs,
                                                 float* __restrict__ y) {
    using G = Geom<K, S, PAD, HIN, WIN, HOUT, WOUT, TW>;
    constexpr int SLOTS_W = G::SLOTS_W;
    constexpr int NW = TCO * CIN * K * K;

    __shared__ float wlds[NW];

    const int zz  = blockIdx.z;
    const int b   = zz / (COUT / TCO);
    const int cob = (zz % (COUT / TCO)) * TCO;

    for (int i = threadIdx.x; i < NW; i += 256) {
        int t    = i % TCO;
        int rest = i / TCO;
        wlds[i] = w[(size_t)(cob + t) * (CIN * K * K) + rest];
    }
    __syncthreads();

    const int s = blockIdx.x * 256 + threadIdx.x;
    if (s >= G::N_EDGE) return;

    // edge ring = top rows + bottom rows + left strip + right strip
    constexpr int TOPN = G::HO_LO * SLOTS_W;
    constexpr int BOTN = (HOUT - G::HO_HI) * SLOTS_W;
    constexpr int MIDH = G::HO_HI - G::HO_LO;
    constexpr int LW   = G::WS_LO;
    constexpr int RW   = SLOTS_W - G::WS_HI;
    constexpr int LN   = MIDH * LW;

    int ho = 0, ws = 0;
    if (s < TOPN) {
        ho = s / SLOTS_W;
        ws = s % SLOTS_W;
    } else if (s < TOPN + BOTN) {
        int t = s - TOPN;
        ho = G::HO_HI + t / SLOTS_W;
        ws = t % SLOTS_W;
    } else if (s < TOPN + BOTN + LN) {
        int t = s - TOPN - BOTN;
        constexpr int D = LW > 0 ? LW : 1;
        ho = G::HO_LO + t / D;
        ws = t % D;
    } else {
        int t = s - TOPN - BOTN - LN;
        constexpr int D = RW > 0 ? RW : 1;
        ho = G::HO_LO + t / D;
        ws = G::WS_HI + t % D;
    }
    const int wo = ws * TW;

    const float* xb = x + (size_t)b * CIN * HIN * WIN;

    float acc[TCO][TW];
#pragma unroll
    for (int t = 0; t < TCO; ++t) {
        float bv = bs[cob + t];
#pragma unroll
        for (int j = 0; j < TW; ++j) acc[t][j] = bv;
    }

    const int hi0 = ho * S - PAD;
    const int wi0 = wo * S - PAD;

#pragma unroll 2
    for (int ci = 0; ci < CIN; ++ci) {
        const float* xc = xb + (size_t)ci * HIN * WIN;
        const float* wc = &wlds[(ci * K * K) * TCO];
#pragma unroll
        for (int kh = 0; kh < K; ++kh) {
            const int hi = hi0 + kh;
            const bool rowok = (unsigned)hi < (unsigned)HIN;
            const float* xr = xc + (size_t)(rowok ? hi : 0) * WIN;
            float r[G::L];
#pragma unroll
            for (int u = 0; u < G::L; ++u) {
                const int wi = wi0 + u;
                const bool ok = rowok && (unsigned)wi < (unsigned)WIN;
                const float v = xr[ok ? wi : 0];
                r[u] = ok ? v : 0.0f;
            }
#pragma unroll
            for (int kw = 0; kw < K; ++kw) {
                const float* wg = wc + (kh * K + kw) * TCO;
                float w8[TCO];
#pragma unroll
                for (int t = 0; t < TCO; ++t) w8[t] = wg[t];
#pragma unroll
                for (int j = 0; j < TW; ++j) {
                    const float xv = r[kw + j * S];
#pragma unroll
                    for (int t = 0; t < TCO; ++t)
                        acc[t][j] = fmaf(xv, w8[t], acc[t][j]);
                }
            }
        }
    }

#pragma unroll
    for (int t = 0; t < TCO; ++t) {
        float* yr = y + (((size_t)b * COUT + cob + t) * HOUT + ho) * WOUT + wo;
#pragma unroll
        for (int j = 0; j < TW; ++j) {
            const float v = acc[t][j];
            yr[j] = v >= 0.0f ? v : NEG_SLOPE * v;
        }
    }
}

// ---------------- bilinear warp (B=4, H=12, W=24) ----------------
__global__ void warp_kernel(const float* __restrict__ img, const float* __restrict__ flow,
                            float* __restrict__ out, int C) {
    const int H = 12, W = 24, HW = 288;
    int idx = blockIdx.x * blockDim.x + threadIdx.x;
    int total = 4 * C * HW;
    if (idx >= total) return;
    int w = idx % W;
    int h = (idx / W) % H;
    int c = (idx / HW) % C;
    int b = idx / (HW * C);

    float fx = flow[(((size_t)b * 2 + 0) * H + h) * W + w] * 0.625f;
    float fy = flow[(((size_t)b * 2 + 1) * H + h) * W + w] * 0.625f;
    float px = (float)w + fx;
    float py = (float)h + fy;
    float x0f = floorf(px);
    float y0f = floorf(py);
    float wx = px - x0f;
    float wy = py - y0f;
    int x0 = (int)x0f;
    int y0 = (int)y0f;

    const float* ip = img + ((size_t)b * C + c) * HW;
    auto g = [&](int yi, int xi) -> float {
        if (xi < 0 || xi > W - 1 || yi < 0 || yi > H - 1) return 0.0f;
        return ip[yi * W + xi];
    };
    float v = g(y0, x0) * (1.0f - wx) * (1.0f - wy)
            + g(y0, x0 + 1) * wx * (1.0f - wy)
            + g(y0 + 1, x0) * (1.0f - wx) * wy
            + g(y0 + 1, x0 + 1) * wx * wy;
    out[idx] = v;
}

// ---------------- correlation (7x7 disp) + lrelu ----------------
__global__ void corr_lrelu(const float* __restrict__ f1, const float* __restrict__ wp,
                           float* __restrict__ out, int C) {
    const int H = 12, W = 24, HW = 288;
    int idx = blockIdx.x * blockDim.x + threadIdx.x;
    int total = 4 * 49 * HW;
    if (idx >= total) return;
    int w = idx % W;
    int h = (idx / W) % H;
    int d = (idx / HW) % 49;
    int b = idx / (49 * HW);
    int di = d / 7 - 3;
    int dj = d % 7 - 3;
    int h2 = h + di;
    int w2 = w + dj;

    float s = 0.0f;
    if (h2 >= 0 && h2 < H && w2 >= 0 && w2 < W) {
        const float* a = f1 + (size_t)b * C * HW + h * W + w;
        const float* p = wp + (size_t)b * C * HW + h2 * W + w2;
        for (int c = 0; c < C; ++c) s = fmaf(a[(size_t)c * HW], p[(size_t)c * HW], s);
    }
    s /= (float)C;
    s = (s >= 0.0f) ? s : NEG_SLOPE * s;
    out[idx] = s;
}

// ---------------- host ----------------
template <int K, int S, int PAD, int CIN, int COUT,
          int HIN, int WIN, int HOUT, int WOUT, int TCO, int TW>
static void launch_conv(const float* x, const float* w, const float* bs, float* y,
                        hipStream_t stream) {
    using G = Geom<K, S, PAD, HIN, WIN, HOUT, WOUT, TW>;
    const int z = 4 * (COUT / TCO);
    if (G::N_INT > 0)
        conv_int<K, S, PAD, CIN, COUT, HIN, WIN, HOUT, WOUT, TCO, TW>
            <<<dim3(cdiv(G::N_INT, 256), 1, z), 256, 0, stream>>>(x, w, bs, y);
    if (G::N_EDGE > 0)
        conv_edge<K, S, PAD, CIN, COUT, HIN, WIN, HOUT, WOUT, TCO, TW>
            <<<dim3(cdiv(G::N_EDGE, 256), 1, z), 256, 0, stream>>>(x, w, bs, y);
}

extern "C" void kernel_launch(void* const* d_in, const int* in_sizes, int n_in,
                              void* d_out, int out_size, void* d_ws, size_t ws_size,
                              hipStream_t stream) {
    const float* img1 = (const float*)d_in[0];
    const float* img2 = (const float*)d_in[1];
    const float* flow = (const float*)d_in[2];
    float* out = (float*)d_out;

    const float* W[10];
    const float* Bs[10];
    for (int l = 0; l < 10; ++l) {
        W[l]  = (const float*)d_in[3 + 2 * l];
        Bs[l] = (const float*)d_in[4 + 2 * l];
    }

    // ws layout identical to the proven footprint (47.85M floats = 191.4 MB)
    float* ws = (float*)d_ws;
    size_t off = 0;
    float* bufA = ws + off; off += 37748736;  // 4*32*384*768
    float* bufB = ws + off; off += 9437184;   // 4*32*192*384
    float* f1   = ws + off; off += 221184;    // 4*192*12*24
    float* f2   = ws + off; off += 221184;
    float* wrp  = ws + off; off += 221184;

    auto chain = [&](const float* img, float* fout) {
        // L1: 3->32, 7x7 s1 p3, 384x768  (CIN=3: full unroll)
        launch_conv<7,1,3,  3, 32, 384,768, 384,768, 8,4>(img,  W[0], Bs[0], bufA, stream);
        // L2: 32->32, 3x3 s2 p1 -> 192x384
        launch_conv<3,2,1, 32, 32, 384,768, 192,384, 8,4>(bufA, W[1], Bs[1], bufB, stream);
        // L3: 32->32, s1
        launch_conv<3,1,1, 32, 32, 192,384, 192,384, 8,4>(bufB, W[2], Bs[2], bufA, stream);
        // L4: 32->32, s1
        launch_conv<3,1,1, 32, 32, 192,384, 192,384, 8,4>(bufA, W[3], Bs[3], bufB, stream);
        // L5: 32->64, s2 -> 96x192
        launch_conv<3,2,1, 32, 64, 192,384,  96,192, 8,4>(bufB, W[4], Bs[4], bufA, stream);
        // L6: 64->64, s1
        launch_conv<3,1,1, 64, 64,  96,192,  96,192, 8,4>(bufA, W[5], Bs[5], bufB, stream);
        // L7: 64->96, s2 -> 48x96   (TCO=8: restore round-0 reuse for tail layers)
        launch_conv<3,2,1, 64, 96,  96,192,  48, 96, 8,4>(bufB, W[6], Bs[6], bufA, stream);
        // L8: 96->96, s1
        launch_conv<3,1,1, 96, 96,  48, 96,  48, 96, 8,4>(bufA, W[7], Bs[7], bufB, stream);
        // L9: 96->128, s2 -> 24x48
        launch_conv<3,2,1, 96,128,  48, 96,  24, 48, 8,4>(bufB, W[8], Bs[8], bufA, stream);
        // L10: 128->192, s2 -> 12x24 (TW=2: 144 slots/plane at same TCO=8 reuse)
        launch_conv<3,2,1,128,192,  24, 48,  12, 24, 8,2>(bufA, W[9], Bs[9], fout, stream);
    };

    chain(img1, f1);
    chain(img2, f2);

    warp_kernel<<<cdiv(4 * 192 * 288, 256), 256, 0, stream>>>(f2, flow, wrp, 192);
    corr_lrelu<<<cdiv(4 * 49 * 288, 256), 256, 0, stream>>>(f1, wrp, out, 192);
}

// Round 3
// 2514.504 us; speedup vs baseline: 1.5648x; 1.5648x over previous
//
#include <hip/hip_runtime.h>

#define NEG_SLOPE 0.1f

static inline int cdiv(int a, int b) { return (a + b - 1) / b; }

// ---------------- round-0 monolithic blocked conv + leaky relu (L2..L10) ----------------
// Measured-good for CIN>=32 layers: ~1070us per chain. Do not modify without per-layer counters.
template <int K, int S, int PAD, int CIN, int COUT,
          int HIN, int WIN, int HOUT, int WOUT, int TCO, int TW>
__global__ __launch_bounds__(256) void conv_blk(const float* __restrict__ x,
                                                const float* __restrict__ w,
                                                const float* __restrict__ bs,
                                                float* __restrict__ y) {
    constexpr int SLOTS_W = WOUT / TW;      // thread-slots per output row
    constexpr int NSLOT   = HOUT * SLOTS_W; // thread-slots per (b, co_group) plane
    constexpr int NW      = TCO * CIN * K * K;

    __shared__ float wlds[NW];

    const int zz  = blockIdx.z;
    const int b   = zz / (COUT / TCO);
    const int cob = (zz % (COUT / TCO)) * TCO;

    // stage weights: wlds[((ci*K+kh)*K+kw)*TCO + t] = w[(cob+t)][ci][kh][kw]
    for (int i = threadIdx.x; i < NW; i += 256) {
        int t    = i % TCO;
        int rest = i / TCO;                 // = ci*K*K + kh*K + kw
        wlds[i] = w[(size_t)(cob + t) * (CIN * K * K) + rest];
    }
    __syncthreads();

    const int slot = blockIdx.x * 256 + threadIdx.x;
    if (slot >= NSLOT) return;

    const int ho = slot / SLOTS_W;
    const int wo = (slot % SLOTS_W) * TW;

    const float* xb = x + (size_t)b * CIN * HIN * WIN;

    float acc[TCO][TW];
#pragma unroll
    for (int t = 0; t < TCO; ++t) {
        float bv = bs[cob + t];
#pragma unroll
        for (int j = 0; j < TW; ++j) acc[t][j] = bv;
    }

    const int hi0 = ho * S - PAD;
    const int wi0 = wo * S - PAD;
    constexpr int L = (TW - 1) * S + K;     // input columns needed per row
    const bool interior = (hi0 >= 0) && (hi0 + K <= HIN) && (wi0 >= 0) && (wi0 + L <= WIN);

    for (int ci = 0; ci < CIN; ++ci) {
        const float* xc = xb + (size_t)ci * HIN * WIN;
        const float* wc = &wlds[(ci * K * K) * TCO];
#pragma unroll
        for (int kh = 0; kh < K; ++kh) {
            const int hi = hi0 + kh;
            float r[L];
            if (interior) {
                const float* xr = xc + (size_t)hi * WIN + wi0;
#pragma unroll
                for (int u = 0; u < L; ++u) r[u] = xr[u];
            } else {
                const bool rowok = (unsigned)hi < (unsigned)HIN;
#pragma unroll
                for (int u = 0; u < L; ++u) {
                    const int wi = wi0 + u;
                    r[u] = (rowok && (unsigned)wi < (unsigned)WIN)
                               ? xc[(size_t)hi * WIN + wi] : 0.0f;
                }
            }
#pragma unroll
            for (int kw = 0; kw < K; ++kw) {
                const float* wg = wc + (kh * K + kw) * TCO;
                float w8[TCO];
#pragma unroll
                for (int t = 0; t < TCO; ++t) w8[t] = wg[t];
#pragma unroll
                for (int j = 0; j < TW; ++j) {
                    const float xv = r[kw + j * S];
#pragma unroll
                    for (int t = 0; t < TCO; ++t)
                        acc[t][j] = fmaf(xv, w8[t], acc[t][j]);
                }
            }
        }
    }

    // epilogue: leaky relu + store
#pragma unroll
    for (int t = 0; t < TCO; ++t) {
        float* yr = y + (((size_t)b * COUT + cob + t) * HOUT + ho) * WOUT + wo;
#pragma unroll
        for (int j = 0; j < TW; ++j) {
            const float v = acc[t][j];
            yr[j] = v >= 0.0f ? v : NEG_SLOPE * v;
        }
    }
}

// Compile-time geometry: interior rectangle (no bounds checks needed) vs edge ring.
template <int K, int S, int PAD, int HIN, int WIN, int HOUT, int WOUT, int TW>
struct Geom {
    static constexpr int SLOTS_W = WOUT / TW;       // thread-slots per output row
    static constexpr int NSLOT   = HOUT * SLOTS_W;  // slots per (b, co_group) plane
    static constexpr int L       = (TW - 1) * S + K;
    static constexpr int HO_LO   = (PAD + S - 1) / S;
    static constexpr int HO_HI0  = (HIN - K + PAD) / S + 1;
    static constexpr int HO_HI   = HO_HI0 < HOUT ? HO_HI0 : HOUT;
    static constexpr int WS_LO   = (PAD + TW * S - 1) / (TW * S);
    static constexpr int WS_HI0  = (WIN + PAD - L) / (TW * S) + 1;
    static constexpr int WS_HI   = WS_HI0 < SLOTS_W ? WS_HI0 : SLOTS_W;
    static constexpr int WS_N    = WS_HI - WS_LO;
    static constexpr int N_INT   = (HO_HI - HO_LO) * WS_N;
    static constexpr int N_EDGE  = NSLOT - N_INT;
};

// ---------------- interior conv + leaky relu, L1 only (measured 144us) ----------------
template <int K, int S, int PAD, int CIN, int COUT,
          int HIN, int WIN, int HOUT, int WOUT, int TCO, int TW>
__global__ __launch_bounds__(256, 4) void conv_int(const float* __restrict__ x,
                                                   const float* __restrict__ w,
                                                   const float* __restrict__ bs,
                                                   float* __restrict__ y) {
    using G = Geom<K, S, PAD, HIN, WIN, HOUT, WOUT, TW>;
    constexpr int NW = TCO * CIN * K * K;

    __shared__ float wlds[NW];

    const int zz  = blockIdx.z;
    const int b   = zz / (COUT / TCO);
    const int cob = (zz % (COUT / TCO)) * TCO;

    for (int i = threadIdx.x; i < NW; i += 256) {
        int t    = i % TCO;
        int rest = i / TCO;
        wlds[i] = w[(size_t)(cob + t) * (CIN * K * K) + rest];
    }
    __syncthreads();

    const int s = blockIdx.x * 256 + threadIdx.x;
    if (s >= G::N_INT) return;

    const int ho = G::HO_LO + s / G::WS_N;
    const int wo = (G::WS_LO + s % G::WS_N) * TW;

    const float* xb = x + (size_t)b * CIN * HIN * WIN;

    float acc[TCO][TW];
#pragma unroll
    for (int t = 0; t < TCO; ++t) {
        float bv = bs[cob + t];
#pragma unroll
        for (int j = 0; j < TW; ++j) acc[t][j] = bv;
    }

    const int hi0 = ho * S - PAD;
    const int wi0 = wo * S - PAD;

#pragma unroll
    for (int ci = 0; ci < CIN; ++ci) {
        const float* xc = xb + (size_t)ci * HIN * WIN;
        const float* wc = &wlds[(ci * K * K) * TCO];
#pragma unroll
        for (int kh = 0; kh < K; ++kh) {
            const float* xr = xc + (size_t)(hi0 + kh) * WIN + wi0;
            float r[G::L];
#pragma unroll
            for (int u = 0; u < G::L; ++u) r[u] = xr[u];
#pragma unroll
            for (int kw = 0; kw < K; ++kw) {
                const float* wg = wc + (kh * K + kw) * TCO;
                float w8[TCO];
                if constexpr ((TCO % 4) == 0) {
#pragma unroll
                    for (int t = 0; t < TCO; t += 4) {
                        float4 q = *reinterpret_cast<const float4*>(wg + t);
                        w8[t] = q.x; w8[t + 1] = q.y; w8[t + 2] = q.z; w8[t + 3] = q.w;
                    }
                } else {
#pragma unroll
                    for (int t = 0; t < TCO; ++t) w8[t] = wg[t];
                }
#pragma unroll
                for (int j = 0; j < TW; ++j) {
                    const float xv = r[kw + j * S];
#pragma unroll
                    for (int t = 0; t < TCO; ++t)
                        acc[t][j] = fmaf(xv, w8[t], acc[t][j]);
                }
            }
        }
    }

#pragma unroll
    for (int t = 0; t < TCO; ++t) {
        float* yr = y + (((size_t)b * COUT + cob + t) * HOUT + ho) * WOUT + wo;
        float v[TW];
#pragma unroll
        for (int j = 0; j < TW; ++j) {
            const float a = acc[t][j];
            v[j] = a >= 0.0f ? a : NEG_SLOPE * a;
        }
        if constexpr (TW == 4) {
            *reinterpret_cast<float4*>(yr) = make_float4(v[0], v[1], v[2], v[3]);
        } else if constexpr (TW == 2) {
            *reinterpret_cast<float2*>(yr) = make_float2(v[0], v[1]);
        } else {
#pragma unroll
            for (int j = 0; j < TW; ++j) yr[j] = v[j];
        }
    }
}

// ---------------- edge conv + leaky relu, L1 only ----------------
template <int K, int S, int PAD, int CIN, int COUT,
          int HIN, int WIN, int HOUT, int WOUT, int TCO, int TW>
__global__ __launch_bounds__(256) void conv_edge(const float* __restrict__ x,
                                                 const float* __restrict__ w,
                                                 const float* __restrict__ bs,
                                                 float* __restrict__ y) {
    using G = Geom<K, S, PAD, HIN, WIN, HOUT, WOUT, TW>;
    constexpr int SLOTS_W = G::SLOTS_W;
    constexpr int NW = TCO * CIN * K * K;

    __shared__ float wlds[NW];

    const int zz  = blockIdx.z;
    const int b   = zz / (COUT / TCO);
    const int cob = (zz % (COUT / TCO)) * TCO;

    for (int i = threadIdx.x; i < NW; i += 256) {
        int t    = i % TCO;
        int rest = i / TCO;
        wlds[i] = w[(size_t)(cob + t) * (CIN * K * K) + rest];
    }
    __syncthreads();

    const int s = blockIdx.x * 256 + threadIdx.x;
    if (s >= G::N_EDGE) return;

    constexpr int TOPN = G::HO_LO * SLOTS_W;
    constexpr int BOTN = (HOUT - G::HO_HI) * SLOTS_W;
    constexpr int MIDH = G::HO_HI - G::HO_LO;
    constexpr int LW   = G::WS_LO;
    constexpr int RW   = SLOTS_W - G::WS_HI;
    constexpr int LN   = MIDH * LW;

    int ho = 0, ws = 0;
    if (s < TOPN) {
        ho = s / SLOTS_W;
        ws = s % SLOTS_W;
    } else if (s < TOPN + BOTN) {
        int t = s - TOPN;
        ho = G::HO_HI + t / SLOTS_W;
        ws = t % SLOTS_W;
    } else if (s < TOPN + BOTN + LN) {
        int t = s - TOPN - BOTN;
        constexpr int D = LW > 0 ? LW : 1;
        ho = G::HO_LO + t / D;
        ws = t % D;
    } else {
        int t = s - TOPN - BOTN - LN;
        constexpr int D = RW > 0 ? RW : 1;
        ho = G::HO_LO + t / D;
        ws = G::WS_HI + t % D;
    }
    const int wo = ws * TW;

    const float* xb = x + (size_t)b * CIN * HIN * WIN;

    float acc[TCO][TW];
#pragma unroll
    for (int t = 0; t < TCO; ++t) {
        float bv = bs[cob + t];
#pragma unroll
        for (int j = 0; j < TW; ++j) acc[t][j] = bv;
    }

    const int hi0 = ho * S - PAD;
    const int wi0 = wo * S - PAD;

#pragma unroll 2
    for (int ci = 0; ci < CIN; ++ci) {
        const float* xc = xb + (size_t)ci * HIN * WIN;
        const float* wc = &wlds[(ci * K * K) * TCO];
#pragma unroll
        for (int kh = 0; kh < K; ++kh) {
            const int hi = hi0 + kh;
            const bool rowok = (unsigned)hi < (unsigned)HIN;
            const float* xr = xc + (size_t)(rowok ? hi : 0) * WIN;
            float r[G::L];
#pragma unroll
            for (int u = 0; u < G::L; ++u) {
                const int wi = wi0 + u;
                const bool ok = rowok && (unsigned)wi < (unsigned)WIN;
                const float v = xr[ok ? wi : 0];
                r[u] = ok ? v : 0.0f;
            }
#pragma unroll
            for (int kw = 0; kw < K; ++kw) {
                const float* wg = wc + (kh * K + kw) * TCO;
                float w8[TCO];
#pragma unroll
                for (int t = 0; t < TCO; ++t) w8[t] = wg[t];
#pragma unroll
                for (int j = 0; j < TW; ++j) {
                    const float xv = r[kw + j * S];
#pragma unroll
                    for (int t = 0; t < TCO; ++t)
                        acc[t][j] = fmaf(xv, w8[t], acc[t][j]);
                }
            }
        }
    }

#pragma unroll
    for (int t = 0; t < TCO; ++t) {
        float* yr = y + (((size_t)b * COUT + cob + t) * HOUT + ho) * WOUT + wo;
#pragma unroll
        for (int j = 0; j < TW; ++j) {
            const float v = acc[t][j];
            yr[j] = v >= 0.0f ? v : NEG_SLOPE * v;
        }
    }
}

// ---------------- bilinear warp (B=4, H=12, W=24) ----------------
__global__ void warp_kernel(const float* __restrict__ img, const float* __restrict__ flow,
                            float* __restrict__ out, int C) {
    const int H = 12, W = 24, HW = 288;
    int idx = blockIdx.x * blockDim.x + threadIdx.x;
    int total = 4 * C * HW;
    if (idx >= total) return;
    int w = idx % W;
    int h = (idx / W) % H;
    int c = (idx / HW) % C;
    int b = idx / (HW * C);

    float fx = flow[(((size_t)b * 2 + 0) * H + h) * W + w] * 0.625f;
    float fy = flow[(((size_t)b * 2 + 1) * H + h) * W + w] * 0.625f;
    float px = (float)w + fx;
    float py = (float)h + fy;
    float x0f = floorf(px);
    float y0f = floorf(py);
    float wx = px - x0f;
    float wy = py - y0f;
    int x0 = (int)x0f;
    int y0 = (int)y0f;

    const float* ip = img + ((size_t)b * C + c) * HW;
    auto g = [&](int yi, int xi) -> float {
        if (xi < 0 || xi > W - 1 || yi < 0 || yi > H - 1) return 0.0f;
        return ip[yi * W + xi];
    };
    float v = g(y0, x0) * (1.0f - wx) * (1.0f - wy)
            + g(y0, x0 + 1) * wx * (1.0f - wy)
            + g(y0 + 1, x0) * (1.0f - wx) * wy
            + g(y0 + 1, x0 + 1) * wx * wy;
    out[idx] = v;
}

// ---------------- correlation (7x7 disp) + lrelu ----------------
__global__ void corr_lrelu(const float* __restrict__ f1, const float* __restrict__ wp,
                           float* __restrict__ out, int C) {
    const int H = 12, W = 24, HW = 288;
    int idx = blockIdx.x * blockDim.x + threadIdx.x;
    int total = 4 * 49 * HW;
    if (idx >= total) return;
    int w = idx % W;
    int h = (idx / W) % H;
    int d = (idx / HW) % 49;
    int b = idx / (49 * HW);
    int di = d / 7 - 3;
    int dj = d % 7 - 3;
    int h2 = h + di;
    int w2 = w + dj;

    float s = 0.0f;
    if (h2 >= 0 && h2 < H && w2 >= 0 && w2 < W) {
        const float* a = f1 + (size_t)b * C * HW + h * W + w;
        const float* p = wp + (size_t)b * C * HW + h2 * W + w2;
        for (int c = 0; c < C; ++c) s = fmaf(a[(size_t)c * HW], p[(size_t)c * HW], s);
    }
    s /= (float)C;
    s = (s >= 0.0f) ? s : NEG_SLOPE * s;
    out[idx] = s;
}

// ---------------- host ----------------
extern "C" void kernel_launch(void* const* d_in, const int* in_sizes, int n_in,
                              void* d_out, int out_size, void* d_ws, size_t ws_size,
                              hipStream_t stream) {
    const float* img1 = (const float*)d_in[0];
    const float* img2 = (const float*)d_in[1];
    const float* flow = (const float*)d_in[2];
    float* out = (float*)d_out;

    const float* W[10];
    const float* Bs[10];
    for (int l = 0; l < 10; ++l) {
        W[l]  = (const float*)d_in[3 + 2 * l];
        Bs[l] = (const float*)d_in[4 + 2 * l];
    }

    // ws layout identical to the proven footprint (47.85M floats = 191.4 MB)
    float* ws = (float*)d_ws;
    size_t off = 0;
    float* bufA = ws + off; off += 37748736;  // 4*32*384*768
    float* bufB = ws + off; off += 9437184;   // 4*32*192*384
    float* f1   = ws + off; off += 221184;    // 4*192*12*24
    float* f2   = ws + off; off += 221184;
    float* wrp  = ws + off; off += 221184;

    auto chain = [&](const float* img, float* fout) {
        // L1: 3->32, 7x7 s1 p3, 384x768 — split int/edge (measured 497us -> 144us)
        {
            using G = Geom<7,1,3, 384,768, 384,768, 4>;
            conv_int<7,1,3,  3, 32, 384,768, 384,768, 8,4>
                <<<dim3(cdiv(G::N_INT, 256), 1, 4*(32/8)), 256, 0, stream>>>(img, W[0], Bs[0], bufA);
            conv_edge<7,1,3,  3, 32, 384,768, 384,768, 8,4>
                <<<dim3(cdiv(G::N_EDGE, 256), 1, 4*(32/8)), 256, 0, stream>>>(img, W[0], Bs[0], bufA);
        }
        // L2..L10: round-0 monolithic conv_blk (measured-good; unmodified)
        conv_blk<3,2,1, 32, 32, 384,768, 192,384, 8,4>
            <<<dim3(cdiv(192*(384/4),256),1,4*(32/8)), 256, 0, stream>>>(bufA, W[1], Bs[1], bufB);
        conv_blk<3,1,1, 32, 32, 192,384, 192,384, 8,4>
            <<<dim3(cdiv(192*(384/4),256),1,4*(32/8)), 256, 0, stream>>>(bufB, W[2], Bs[2], bufA);
        conv_blk<3,1,1, 32, 32, 192,384, 192,384, 8,4>
            <<<dim3(cdiv(192*(384/4),256),1,4*(32/8)), 256, 0, stream>>>(bufA, W[3], Bs[3], bufB);
        conv_blk<3,2,1, 32, 64, 192,384,  96,192, 8,4>
            <<<dim3(cdiv(96*(192/4),256),1,4*(64/8)), 256, 0, stream>>>(bufB, W[4], Bs[4], bufA);
        conv_blk<3,1,1, 64, 64,  96,192,  96,192, 8,4>
            <<<dim3(cdiv(96*(192/4),256),1,4*(64/8)), 256, 0, stream>>>(bufA, W[5], Bs[5], bufB);
        conv_blk<3,2,1, 64, 96,  96,192,  48, 96, 8,4>
            <<<dim3(cdiv(48*(96/4),256),1,4*(96/8)), 256, 0, stream>>>(bufB, W[6], Bs[6], bufA);
        conv_blk<3,1,1, 96, 96,  48, 96,  48, 96, 8,4>
            <<<dim3(cdiv(48*(96/4),256),1,4*(96/8)), 256, 0, stream>>>(bufA, W[7], Bs[7], bufB);
        conv_blk<3,2,1, 96,128,  48, 96,  24, 48, 8,4>
            <<<dim3(cdiv(24*(48/4),256),1,4*(128/8)), 256, 0, stream>>>(bufB, W[8], Bs[8], bufA);
        conv_blk<3,2,1,128,192,  24, 48,  12, 24, 8,4>
            <<<dim3(cdiv(12*(24/4),256),1,4*(192/8)), 256, 0, stream>>>(bufA, W[9], Bs[9], fout);
    };

    chain(img1, f1);
    chain(img2, f2);

    warp_kernel<<<cdiv(4 * 192 * 288, 256), 256, 0, stream>>>(f2, flow, wrp, 192);
    corr_lrelu<<<cdiv(4 * 49 * 288, 256), 256, 0, stream>>>(f1, wrp, out, 192);
}